// Round 3
// baseline (498.250 us; speedup 1.0000x reference)
//
#include <hip/hip_runtime.h>
#include <stdint.h>

#define B_ 4
#define S_ 2048
#define H_ 1024
#define NH_ 16
#define HD_ 64

typedef __bf16 bf16x8 __attribute__((ext_vector_type(8)));
typedef unsigned short u16x8 __attribute__((ext_vector_type(8)));
typedef float f32x4 __attribute__((ext_vector_type(4)));

__device__ __forceinline__ unsigned short f2bf(float x) {
  union { float f; unsigned u; } c; c.f = x;
  unsigned r = (c.u + 0x7FFFu + ((c.u >> 16) & 1u)) >> 16;
  return (unsigned short)r;
}

__device__ __forceinline__ void gload16(const unsigned short* g, unsigned short* lds) {
  __builtin_amdgcn_global_load_lds((const __attribute__((address_space(1))) void*)g,
                                   (__attribute__((address_space(3))) void*)lds, 16, 0, 0);
}

// ---------------- fp32 -> bf16 cast ----------------
__global__ __launch_bounds__(256) void cvt_kernel(const float* __restrict__ src,
                                                  unsigned short* __restrict__ dst, int n) {
  int i = (blockIdx.x * blockDim.x + threadIdx.x) * 4;
  if (i < n) {
    float4 v = *reinterpret_cast<const float4*>(src + i);
    ushort4 o;
    o.x = f2bf(v.x); o.y = f2bf(v.y); o.z = f2bf(v.z); o.w = f2bf(v.w);
    *reinterpret_cast<ushort4*>(dst + i) = o;
  }
}

// ---------------- bf16 GEMM, C[m,n] = sum_k A[m,k]*B[n,k] + bias[n] ----------------
// 128x128 tile, BK=32, 256 threads (4 waves, 2x2), global_load_lds staging.
template <bool BF16OUT>
__global__ __launch_bounds__(256) void gemm_bt(const unsigned short* __restrict__ A,
                                               const unsigned short* __restrict__ Bm,
                                               const float* __restrict__ bias,
                                               void* __restrict__ Cout,
                                               int M, int N, int K) {
  __shared__ unsigned short As[128 * 32];
  __shared__ unsigned short Bs[128 * 32];
  const int t = threadIdx.x;
  const int lane = t & 63;
  const int wv = t >> 6;
  const int wm = wv >> 1, wn = wv & 1;
  const int m0 = blockIdx.x * 128, n0 = blockIdx.y * 128;
  const int l15 = lane & 15, g8 = (lane >> 4) * 8;

  f32x4 acc[4][4];
#pragma unroll
  for (int i = 0; i < 4; ++i)
#pragma unroll
    for (int j = 0; j < 4; ++j) { f32x4 z = {0.f, 0.f, 0.f, 0.f}; acc[i][j] = z; }

  const int rowA = t >> 2;           // 0..63
  const int colA = (t & 3) * 8;      // 0,8,16,24
  const unsigned short* gA0 = A + (long)(m0 + rowA) * K + colA;
  const unsigned short* gA1 = A + (long)(m0 + 64 + rowA) * K + colA;
  const unsigned short* gB0 = Bm + (long)(n0 + rowA) * K + colA;
  const unsigned short* gB1 = Bm + (long)(n0 + 64 + rowA) * K + colA;
  unsigned short* ldsA0 = &As[wv * 512];
  unsigned short* ldsA1 = &As[2048 + wv * 512];
  unsigned short* ldsB0 = &Bs[wv * 512];
  unsigned short* ldsB1 = &Bs[2048 + wv * 512];

  for (int k0 = 0; k0 < K; k0 += 32) {
    __syncthreads();
    gload16(gA0 + k0, ldsA0);
    gload16(gA1 + k0, ldsA1);
    gload16(gB0 + k0, ldsB0);
    gload16(gB1 + k0, ldsB1);
    __syncthreads();

    bf16x8 af[4], bfr[4];
#pragma unroll
    for (int i = 0; i < 4; ++i)
      af[i] = *reinterpret_cast<const bf16x8*>(&As[(wm * 64 + i * 16 + l15) * 32 + g8]);
#pragma unroll
    for (int j = 0; j < 4; ++j)
      bfr[j] = *reinterpret_cast<const bf16x8*>(&Bs[(wn * 64 + j * 16 + l15) * 32 + g8]);
#pragma unroll
    for (int i = 0; i < 4; ++i)
#pragma unroll
      for (int j = 0; j < 4; ++j)
        acc[i][j] = __builtin_amdgcn_mfma_f32_16x16x32_bf16(af[i], bfr[j], acc[i][j], 0, 0, 0);
  }

  const int r0 = (lane >> 4) * 4;
#pragma unroll
  for (int i = 0; i < 4; ++i)
#pragma unroll
    for (int j = 0; j < 4; ++j) {
      int col = n0 + wn * 64 + j * 16 + l15;
      float bv = bias[col];
#pragma unroll
      for (int r = 0; r < 4; ++r) {
        int row = m0 + wm * 64 + i * 16 + r0 + r;
        float v = acc[i][j][r] + bv;
        if (BF16OUT)
          ((unsigned short*)Cout)[(long)row * N + col] = f2bf(v);
        else
          ((float*)Cout)[(long)row * N + col] = v;
      }
    }
}

// ---------------- flash attention ----------------
// grid (S/64, NH, B), 256 threads. Wave w handles 16 q-rows. KV tile = 64.
__global__ __launch_bounds__(256) void attn_kernel(const unsigned short* __restrict__ Q,
                                                   const unsigned short* __restrict__ Kg,
                                                   const unsigned short* __restrict__ Vg,
                                                   const float* __restrict__ mask,
                                                   unsigned short* __restrict__ ctx) {
  __shared__ unsigned short Kt[64 * 72];    // [kv][d] padded
  __shared__ unsigned short VtT[64 * 72];   // [d][kv] padded (transposed)
  __shared__ unsigned short Ps[4 * 16 * 72];

  const int t = threadIdx.x, lane = t & 63, wv = t >> 6;
  const int h = blockIdx.y, b = blockIdx.z;
  const int q0 = blockIdx.x * 64 + wv * 16;
  const int l15 = lane & 15, g8 = (lane >> 4) * 8;
  const long headoff = (long)h * HD_;

  const unsigned short* Qrow = Q + ((long)(b * S_ + q0 + l15)) * H_ + headoff;
  bf16x8 aq0 = *reinterpret_cast<const bf16x8*>(Qrow + g8);
  bf16x8 aq1 = *reinterpret_cast<const bf16x8*>(Qrow + 32 + g8);

  f32x4 o[4];
  float m[4], lsum[4];
#pragma unroll
  for (int d = 0; d < 4; ++d) { f32x4 z = {0.f, 0.f, 0.f, 0.f}; o[d] = z; }
#pragma unroll
  for (int r = 0; r < 4; ++r) { m[r] = -3.0e38f; lsum[r] = 0.f; }

  unsigned short* Pw = &Ps[wv * 16 * 72];
  const float L2E = 1.44269504088896f;

  for (int kv0 = 0; kv0 < S_; kv0 += 64) {
    __syncthreads();
    // stage K and transposed V
#pragma unroll
    for (int it = 0; it < 2; ++it) {
      int job = t + it * 256;
      int row = job >> 3, cg = (job & 7) * 8;
      const unsigned short* kp = Kg + ((long)(b * S_ + kv0 + row)) * H_ + headoff + cg;
      const unsigned short* vp = Vg + ((long)(b * S_ + kv0 + row)) * H_ + headoff + cg;
      u16x8 kvv = *reinterpret_cast<const u16x8*>(kp);
      *reinterpret_cast<u16x8*>(&Kt[row * 72 + cg]) = kvv;
      u16x8 vvv = *reinterpret_cast<const u16x8*>(vp);
#pragma unroll
      for (int j = 0; j < 8; ++j) VtT[(cg + j) * 72 + row] = vvv[j];
    }
    __syncthreads();

    // QK^T -> s[4] tiles (16 q x 64 kv per wave)
    f32x4 s[4];
#pragma unroll
    for (int c = 0; c < 4; ++c) {
      f32x4 z = {0.f, 0.f, 0.f, 0.f};
      bf16x8 k0f = *reinterpret_cast<const bf16x8*>(&Kt[(c * 16 + l15) * 72 + g8]);
      bf16x8 k1f = *reinterpret_cast<const bf16x8*>(&Kt[(c * 16 + l15) * 72 + 32 + g8]);
      z = __builtin_amdgcn_mfma_f32_16x16x32_bf16(aq0, k0f, z, 0, 0, 0);
      z = __builtin_amdgcn_mfma_f32_16x16x32_bf16(aq1, k1f, z, 0, 0, 0);
      s[c] = z;
    }
    float bs[4];
#pragma unroll
    for (int c = 0; c < 4; ++c)
      bs[c] = (1.f - mask[b * S_ + kv0 + c * 16 + l15]) * -10000.f;
#pragma unroll
    for (int c = 0; c < 4; ++c)
#pragma unroll
      for (int r = 0; r < 4; ++r) s[c][r] = s[c][r] * 0.125f + bs[c];

    // online softmax per row
#pragma unroll
    for (int r = 0; r < 4; ++r) {
      float mx = fmaxf(fmaxf(s[0][r], s[1][r]), fmaxf(s[2][r], s[3][r]));
#pragma unroll
      for (int d = 1; d < 16; d <<= 1) mx = fmaxf(mx, __shfl_xor(mx, d));
      float mn = fmaxf(m[r], mx);
      float al = exp2f((m[r] - mn) * L2E);
      m[r] = mn;
      float ps = 0.f;
#pragma unroll
      for (int c = 0; c < 4; ++c) {
        float p = exp2f((s[c][r] - mn) * L2E);
        s[c][r] = p;
        ps += p;
      }
#pragma unroll
      for (int d = 1; d < 16; d <<= 1) ps += __shfl_xor(ps, d);
      lsum[r] = lsum[r] * al + ps;
#pragma unroll
      for (int dt = 0; dt < 4; ++dt) o[dt][r] *= al;
    }

    // P -> LDS (bf16), re-fragment for PV
#pragma unroll
    for (int c = 0; c < 4; ++c)
#pragma unroll
      for (int r = 0; r < 4; ++r)
        Pw[((lane >> 4) * 4 + r) * 72 + c * 16 + l15] = f2bf(s[c][r]);
    __syncthreads();

    bf16x8 pa0 = *reinterpret_cast<const bf16x8*>(&Pw[l15 * 72 + g8]);
    bf16x8 pa1 = *reinterpret_cast<const bf16x8*>(&Pw[l15 * 72 + 32 + g8]);
#pragma unroll
    for (int dt = 0; dt < 4; ++dt) {
      bf16x8 v0f = *reinterpret_cast<const bf16x8*>(&VtT[(dt * 16 + l15) * 72 + g8]);
      bf16x8 v1f = *reinterpret_cast<const bf16x8*>(&VtT[(dt * 16 + l15) * 72 + 32 + g8]);
      o[dt] = __builtin_amdgcn_mfma_f32_16x16x32_bf16(pa0, v0f, o[dt], 0, 0, 0);
      o[dt] = __builtin_amdgcn_mfma_f32_16x16x32_bf16(pa1, v1f, o[dt], 0, 0, 0);
    }
  }

  // epilogue
#pragma unroll
  for (int dt = 0; dt < 4; ++dt)
#pragma unroll
    for (int r = 0; r < 4; ++r) {
      float val = o[dt][r] / lsum[r];
      int q = q0 + (lane >> 4) * 4 + r;
      ctx[((long)(b * S_ + q)) * H_ + headoff + dt * 16 + l15] = f2bf(val);
    }
}

// ---------------- residual + LayerNorm ----------------
__global__ __launch_bounds__(256) void ln_kernel(const float* __restrict__ proj,
                                                 const float* __restrict__ hs,
                                                 const float* __restrict__ gam,
                                                 const float* __restrict__ bet,
                                                 float* __restrict__ out) {
  const int row = blockIdx.x;
  const int t = threadIdx.x;
  const long base = (long)row * H_ + t * 4;
  float4 a = *reinterpret_cast<const float4*>(proj + base);
  float4 hv = *reinterpret_cast<const float4*>(hs + base);
  float x0 = a.x + hv.x, x1 = a.y + hv.y, x2 = a.z + hv.z, x3 = a.w + hv.w;
  float s1 = x0 + x1 + x2 + x3;
  float s2 = x0 * x0 + x1 * x1 + x2 * x2 + x3 * x3;
#pragma unroll
  for (int off = 1; off < 64; off <<= 1) {
    s1 += __shfl_xor(s1, off);
    s2 += __shfl_xor(s2, off);
  }
  __shared__ float a1[4], a2[4];
  if ((t & 63) == 0) { a1[t >> 6] = s1; a2[t >> 6] = s2; }
  __syncthreads();
  float ts1 = a1[0] + a1[1] + a1[2] + a1[3];
  float ts2 = a2[0] + a2[1] + a2[2] + a2[3];
  float mu = ts1 * (1.0f / H_);
  float var = ts2 * (1.0f / H_) - mu * mu;
  float inv = rsqrtf(var + 1e-12f);
  float4 g = *reinterpret_cast<const float4*>(gam + t * 4);
  float4 bb = *reinterpret_cast<const float4*>(bet + t * 4);
  float4 ov;
  ov.x = (x0 - mu) * inv * g.x + bb.x;
  ov.y = (x1 - mu) * inv * g.y + bb.y;
  ov.z = (x2 - mu) * inv * g.z + bb.z;
  ov.w = (x3 - mu) * inv * g.w + bb.w;
  *reinterpret_cast<float4*>(out + base) = ov;
}

extern "C" void kernel_launch(void* const* d_in, const int* in_sizes, int n_in,
                              void* d_out, int out_size, void* d_ws, size_t ws_size,
                              hipStream_t stream) {
  const float* hs   = (const float*)d_in[0];
  const float* mask = (const float*)d_in[1];
  const float* Wq   = (const float*)d_in[2];
  const float* bq   = (const float*)d_in[3];
  const float* Wk   = (const float*)d_in[4];
  const float* bk   = (const float*)d_in[5];
  const float* Wv   = (const float*)d_in[6];
  const float* bv   = (const float*)d_in[7];
  const float* Wd   = (const float*)d_in[8];
  const float* bd   = (const float*)d_in[9];
  const float* lng  = (const float*)d_in[10];
  const float* lnb  = (const float*)d_in[11];
  float* out = (float*)d_out;

  char* ws = (char*)d_ws;
  const size_t SZ_X = (size_t)B_ * S_ * H_ * 2;   // 16 MB bf16
  const size_t SZ_W = (size_t)H_ * H_ * 2;        // 2 MB bf16
  unsigned short* Xb  = (unsigned short*)(ws);
  unsigned short* Wqb = (unsigned short*)(ws + SZ_X);
  unsigned short* Wkb = (unsigned short*)(ws + SZ_X + SZ_W);
  unsigned short* Wvb = (unsigned short*)(ws + SZ_X + 2 * SZ_W);
  unsigned short* Wdb = (unsigned short*)(ws + SZ_X + 3 * SZ_W);
  unsigned short* Qb  = (unsigned short*)(ws + SZ_X + 4 * SZ_W);
  unsigned short* Kb  = (unsigned short*)(ws + 2 * SZ_X + 4 * SZ_W);
  unsigned short* Vb  = (unsigned short*)(ws + 3 * SZ_X + 4 * SZ_W);
  unsigned short* Cxb = (unsigned short*)(ws + 4 * SZ_X + 4 * SZ_W);
  float* Proj         = (float*)(ws + 5 * SZ_X + 4 * SZ_W);

  const int NX = B_ * S_ * H_;  // 8388608
  const int NW = H_ * H_;       // 1048576

  cvt_kernel<<<NX / 1024, 256, 0, stream>>>(hs, Xb, NX);
  cvt_kernel<<<NW / 1024, 256, 0, stream>>>(Wq, Wqb, NW);
  cvt_kernel<<<NW / 1024, 256, 0, stream>>>(Wk, Wkb, NW);
  cvt_kernel<<<NW / 1024, 256, 0, stream>>>(Wv, Wvb, NW);
  cvt_kernel<<<NW / 1024, 256, 0, stream>>>(Wd, Wdb, NW);

  dim3 gg(B_ * S_ / 128, H_ / 128);  // (64, 8)
  gemm_bt<true><<<gg, 256, 0, stream>>>(Xb, Wqb, bq, Qb, B_ * S_, H_, H_);
  gemm_bt<true><<<gg, 256, 0, stream>>>(Xb, Wkb, bk, Kb, B_ * S_, H_, H_);
  gemm_bt<true><<<gg, 256, 0, stream>>>(Xb, Wvb, bv, Vb, B_ * S_, H_, H_);

  dim3 ga(S_ / 64, NH_, B_);  // (32, 16, 4)
  attn_kernel<<<ga, 256, 0, stream>>>(Qb, Kb, Vb, mask, Cxb);

  gemm_bt<false><<<gg, 256, 0, stream>>>(Cxb, Wdb, bd, Proj, B_ * S_, H_, H_);

  ln_kernel<<<B_ * S_, 256, 0, stream>>>(Proj, hs, lng, lnb, out);
}

// Round 4
// 344.232 us; speedup vs baseline: 1.4474x; 1.4474x over previous
//
#include <hip/hip_runtime.h>
#include <stdint.h>

#define B_ 4
#define S_ 2048
#define H_ 1024
#define NH_ 16
#define HD_ 64

typedef __bf16 bf16x8 __attribute__((ext_vector_type(8)));
typedef unsigned short u16x8 __attribute__((ext_vector_type(8)));
typedef float f32x4 __attribute__((ext_vector_type(4)));

__device__ __forceinline__ unsigned short f2bf(float x) {
  union { float f; unsigned u; } c; c.f = x;
  unsigned r = (c.u + 0x7FFFu + ((c.u >> 16) & 1u)) >> 16;
  return (unsigned short)r;
}

__device__ __forceinline__ void gload16(const unsigned short* g, unsigned short* lds) {
  __builtin_amdgcn_global_load_lds((const __attribute__((address_space(1))) void*)g,
                                   (__attribute__((address_space(3))) void*)lds, 16, 0, 0);
}

// ---------------- fp32 -> bf16 cast ----------------
__global__ __launch_bounds__(256) void cvt_kernel(const float* __restrict__ src,
                                                  unsigned short* __restrict__ dst, int n) {
  int i = (blockIdx.x * blockDim.x + threadIdx.x) * 4;
  if (i < n) {
    float4 v = *reinterpret_cast<const float4*>(src + i);
    ushort4 o;
    o.x = f2bf(v.x); o.y = f2bf(v.y); o.z = f2bf(v.z); o.w = f2bf(v.w);
    *reinterpret_cast<ushort4*>(dst + i) = o;
  }
}

// ---------------- bf16 GEMM, C[m,n] = sum_k A[m,k]*B[n,k] + bias[n] ----------------
template <bool BF16OUT>
__global__ __launch_bounds__(256) void gemm_bt(const unsigned short* __restrict__ A,
                                               const unsigned short* __restrict__ Bm,
                                               const float* __restrict__ bias,
                                               void* __restrict__ Cout,
                                               int M, int N, int K) {
  __shared__ unsigned short As[128 * 32];
  __shared__ unsigned short Bs[128 * 32];
  const int t = threadIdx.x;
  const int lane = t & 63;
  const int wv = t >> 6;
  const int wm = wv >> 1, wn = wv & 1;
  const int m0 = blockIdx.x * 128, n0 = blockIdx.y * 128;
  const int l15 = lane & 15, g8 = (lane >> 4) * 8;

  f32x4 acc[4][4];
#pragma unroll
  for (int i = 0; i < 4; ++i)
#pragma unroll
    for (int j = 0; j < 4; ++j) { f32x4 z = {0.f, 0.f, 0.f, 0.f}; acc[i][j] = z; }

  const int rowA = t >> 2;
  const int colA = (t & 3) * 8;
  const unsigned short* gA0 = A + (long)(m0 + rowA) * K + colA;
  const unsigned short* gA1 = A + (long)(m0 + 64 + rowA) * K + colA;
  const unsigned short* gB0 = Bm + (long)(n0 + rowA) * K + colA;
  const unsigned short* gB1 = Bm + (long)(n0 + 64 + rowA) * K + colA;
  unsigned short* ldsA0 = &As[wv * 512];
  unsigned short* ldsA1 = &As[2048 + wv * 512];
  unsigned short* ldsB0 = &Bs[wv * 512];
  unsigned short* ldsB1 = &Bs[2048 + wv * 512];

  for (int k0 = 0; k0 < K; k0 += 32) {
    __syncthreads();
    gload16(gA0 + k0, ldsA0);
    gload16(gA1 + k0, ldsA1);
    gload16(gB0 + k0, ldsB0);
    gload16(gB1 + k0, ldsB1);
    __syncthreads();

    bf16x8 af[4], bfr[4];
#pragma unroll
    for (int i = 0; i < 4; ++i)
      af[i] = *reinterpret_cast<const bf16x8*>(&As[(wm * 64 + i * 16 + l15) * 32 + g8]);
#pragma unroll
    for (int j = 0; j < 4; ++j)
      bfr[j] = *reinterpret_cast<const bf16x8*>(&Bs[(wn * 64 + j * 16 + l15) * 32 + g8]);
#pragma unroll
    for (int i = 0; i < 4; ++i)
#pragma unroll
      for (int j = 0; j < 4; ++j)
        acc[i][j] = __builtin_amdgcn_mfma_f32_16x16x32_bf16(af[i], bfr[j], acc[i][j], 0, 0, 0);
  }

  const int r0 = (lane >> 4) * 4;
#pragma unroll
  for (int i = 0; i < 4; ++i)
#pragma unroll
    for (int j = 0; j < 4; ++j) {
      int col = n0 + wn * 64 + j * 16 + l15;
      float bv = bias[col];
#pragma unroll
      for (int r = 0; r < 4; ++r) {
        int row = m0 + wm * 64 + i * 16 + r0 + r;
        float v = acc[i][j][r] + bv;
        if (BF16OUT)
          ((unsigned short*)Cout)[(long)row * N + col] = f2bf(v);
        else
          ((float*)Cout)[(long)row * N + col] = v;
      }
    }
}

// ---------------- flash attention (swapped QK^T, in-register softmax) ----------------
// grid (S/64, NH, B), 256 threads. Wave w owns 16 q-rows. KV tile = 64.
// Layouts:
//  QK: s = mfma(K_frag, Q_frag) -> s[c][r] = S[kv=16c+4g+r][q=l15], g=lane>>4.
//  Softmax state (m, lsum) per lane: q = l15 (duplicated over 4 groups, kept
//  consistent via xor-16/32 butterflies).
//  PV A-frag rebuilt in-register: word W of frag f (kv = 32f + 8g + jj) comes
//  from lane l15 + 16*(2*(g&1) + (W>>1)), packed word pw[c][W&1], c = (g>>1) + 2f.
//  VtT XOR-swizzle: element (d, kv) stored at d*72 + ((kv&7) | 8*((kv>>3) ^ (d>>3))).
//  Bank check (store, fixed j): bank = (4j + (p&3) + 4*((p>>2)^dc)) % 32 -> 2 lanes/bank (free).
__global__ __launch_bounds__(256) void attn_kernel(const unsigned short* __restrict__ Q,
                                                   const unsigned short* __restrict__ Kg,
                                                   const unsigned short* __restrict__ Vg,
                                                   const float* __restrict__ mask,
                                                   unsigned short* __restrict__ ctx) {
  __shared__ unsigned short Kt[64 * 72];    // [kv][d], padded (+8)
  __shared__ unsigned short VtT[64 * 72];   // [d][kv-swizzled], padded
  __shared__ float biasL[64];               // mask bias, log2 domain

  const int t = threadIdx.x, lane = t & 63;
  const int wv = t >> 6;
  const int h = blockIdx.y, b = blockIdx.z;
  const int q0 = blockIdx.x * 64 + wv * 16;
  const int l15 = lane & 15, g = lane >> 4, g8 = g * 8;
  const long headoff = (long)h * HD_;
  const float L2E = 1.44269504088896f;

  // Q fragment, pre-scaled by 1/sqrt(HD)=0.125 (exact in bf16)
  const unsigned short* Qrow = Q + ((long)(b * S_ + q0 + l15)) * H_ + headoff;
  bf16x8 aq0 = *reinterpret_cast<const bf16x8*>(Qrow + g8);
  bf16x8 aq1 = *reinterpret_cast<const bf16x8*>(Qrow + 32 + g8);
#pragma unroll
  for (int j = 0; j < 8; ++j) {
    aq0[j] = (__bf16)((float)aq0[j] * 0.125f);
    aq1[j] = (__bf16)((float)aq1[j] * 0.125f);
  }

  f32x4 o[4];   // o[dt][r]: col d = dt*16+l15, row q = q0 + 4g + r
#pragma unroll
  for (int d = 0; d < 4; ++d) { f32x4 z = {0.f, 0.f, 0.f, 0.f}; o[d] = z; }
  float mrow = -3.0e38f, lsum = 0.f;  // per lane: q = l15 (log2 domain)

  for (int kv0 = 0; kv0 < S_; kv0 += 64) {
    __syncthreads();
    // ---- stage K (row-major, padded) ----
#pragma unroll
    for (int it = 0; it < 2; ++it) {
      int job = t + it * 256;
      int kv = job >> 3, cg = (job & 7) * 8;
      u16x8 kvv = *reinterpret_cast<const u16x8*>(
          Kg + ((long)(b * S_ + kv0 + kv)) * H_ + headoff + cg);
      *reinterpret_cast<u16x8*>(&Kt[kv * 72 + cg]) = kvv;
    }
    // ---- stage V transposed with XOR swizzle, ushort2 (kv-pair) stores ----
    {
      int p2 = t >> 3, dc = t & 7;
      int kv = p2 * 2;
      const unsigned short* vp0 = Vg + ((long)(b * S_ + kv0 + kv)) * H_ + headoff + dc * 8;
      u16x8 v0 = *reinterpret_cast<const u16x8*>(vp0);
      u16x8 v1 = *reinterpret_cast<const u16x8*>(vp0 + H_);
      int pos = (kv & 7) | (((kv >> 3) ^ dc) << 3);
#pragma unroll
      for (int j = 0; j < 8; ++j) {
        ushort2 pr; pr.x = v0[j]; pr.y = v1[j];
        *reinterpret_cast<ushort2*>(&VtT[(dc * 8 + j) * 72 + pos]) = pr;
      }
    }
    // ---- stage mask bias (log2 domain) ----
    if (t < 64) biasL[t] = (1.f - mask[b * S_ + kv0 + t]) * (-10000.f * L2E);
    __syncthreads();

    // ---- QK^T swapped: s[c][r] = S[16c+4g+r][l15] (pre-scaled) ----
    f32x4 s[4];
#pragma unroll
    for (int c = 0; c < 4; ++c) {
      f32x4 z = {0.f, 0.f, 0.f, 0.f};
      bf16x8 k0 = *reinterpret_cast<const bf16x8*>(&Kt[(c * 16 + l15) * 72 + g8]);
      bf16x8 k1 = *reinterpret_cast<const bf16x8*>(&Kt[(c * 16 + l15) * 72 + 32 + g8]);
      z = __builtin_amdgcn_mfma_f32_16x16x32_bf16(k0, aq0, z, 0, 0, 0);
      z = __builtin_amdgcn_mfma_f32_16x16x32_bf16(k1, aq1, z, 0, 0, 0);
      s[c] = z;
    }
    // to log2 domain + bias
#pragma unroll
    for (int c = 0; c < 4; ++c) {
      f32x4 bb = *reinterpret_cast<const f32x4*>(&biasL[c * 16 + g * 4]);
#pragma unroll
      for (int r = 0; r < 4; ++r) s[c][r] = fmaf(s[c][r], L2E, bb[r]);
    }

    // ---- online softmax: each lane owns full row q=l15 over this tile ----
    float tm = s[0][0];
#pragma unroll
    for (int c = 0; c < 4; ++c)
#pragma unroll
      for (int r = 0; r < 4; ++r) tm = fmaxf(tm, s[c][r]);
    tm = fmaxf(tm, __shfl_xor(tm, 16));
    tm = fmaxf(tm, __shfl_xor(tm, 32));
    float mn = fmaxf(mrow, tm);
    float al = exp2f(mrow - mn);
    mrow = mn;
    float ts = 0.f;
#pragma unroll
    for (int c = 0; c < 4; ++c)
#pragma unroll
      for (int r = 0; r < 4; ++r) {
        float p = exp2f(s[c][r] - mn);
        s[c][r] = p;
        ts += p;
      }
    ts += __shfl_xor(ts, 16);
    ts += __shfl_xor(ts, 32);
    lsum = lsum * al + ts;

    // ---- rescale O (skip when no row's max moved) ----
    if (!__all(al == 1.0f)) {
#pragma unroll
      for (int r = 0; r < 4; ++r) {
        float alr = __shfl(al, 4 * g + r);
#pragma unroll
        for (int dt = 0; dt < 4; ++dt) o[dt][r] *= alr;
      }
    }

    // ---- pack P to bf16 word-pairs: pw[c][h] = (P[16c+4g+2h+1]<<16)|P[16c+4g+2h] ----
    int pw[4][2];
#pragma unroll
    for (int c = 0; c < 4; ++c)
#pragma unroll
      for (int hh = 0; hh < 2; ++hh) {
        union { __bf16 e[2]; int w; } u;
        u.e[0] = (__bf16)s[c][2 * hh];
        u.e[1] = (__bf16)s[c][2 * hh + 1];
        pw[c][hh] = u.w;
      }

    // ---- redistribute to PV A-fragments (in-register transpose) ----
    union { int w[4]; bf16x8 v; } fa0, fa1;
    const int srcbase = l15 + 16 * (2 * (g & 1));
    const bool hiC = (g & 2) != 0;
#pragma unroll
    for (int W = 0; W < 4; ++W) {
      int src = srcbase + 16 * (W >> 1);
      int hh = W & 1;
      int w0 = __shfl(pw[0][hh], src);
      int w1 = __shfl(pw[1][hh], src);
      fa0.w[W] = hiC ? w1 : w0;
      int w2 = __shfl(pw[2][hh], src);
      int w3 = __shfl(pw[3][hh], src);
      fa1.w[W] = hiC ? w3 : w2;
    }

    // ---- PV: o[dt] += P * V ----
#pragma unroll
    for (int dt = 0; dt < 4; ++dt) {
      int d = dt * 16 + l15;
      int sw = ((d >> 3) & 7) * 8;
      bf16x8 v0 = *reinterpret_cast<const bf16x8*>(&VtT[d * 72 + (g8 ^ sw)]);
      bf16x8 v1 = *reinterpret_cast<const bf16x8*>(&VtT[d * 72 + ((32 + g8) ^ sw)]);
      o[dt] = __builtin_amdgcn_mfma_f32_16x16x32_bf16(fa0.v, v0, o[dt], 0, 0, 0);
      o[dt] = __builtin_amdgcn_mfma_f32_16x16x32_bf16(fa1.v, v1, o[dt], 0, 0, 0);
    }
  }

  // ---- epilogue ----
#pragma unroll
  for (int r = 0; r < 4; ++r) {
    float ls = __shfl(lsum, 4 * g + r);
    float inv = 1.0f / ls;
    int q = q0 + 4 * g + r;
#pragma unroll
    for (int dt = 0; dt < 4; ++dt)
      ctx[((long)(b * S_ + q)) * H_ + headoff + dt * 16 + l15] = f2bf(o[dt][r] * inv);
  }
}

// ---------------- residual + LayerNorm ----------------
__global__ __launch_bounds__(256) void ln_kernel(const float* __restrict__ proj,
                                                 const float* __restrict__ hs,
                                                 const float* __restrict__ gam,
                                                 const float* __restrict__ bet,
                                                 float* __restrict__ out) {
  const int row = blockIdx.x;
  const int t = threadIdx.x;
  const long base = (long)row * H_ + t * 4;
  float4 a = *reinterpret_cast<const float4*>(proj + base);
  float4 hv = *reinterpret_cast<const float4*>(hs + base);
  float x0 = a.x + hv.x, x1 = a.y + hv.y, x2 = a.z + hv.z, x3 = a.w + hv.w;
  float s1 = x0 + x1 + x2 + x3;
  float s2 = x0 * x0 + x1 * x1 + x2 * x2 + x3 * x3;
#pragma unroll
  for (int off = 1; off < 64; off <<= 1) {
    s1 += __shfl_xor(s1, off);
    s2 += __shfl_xor(s2, off);
  }
  __shared__ float a1[4], a2[4];
  if ((t & 63) == 0) { a1[t >> 6] = s1; a2[t >> 6] = s2; }
  __syncthreads();
  float ts1 = a1[0] + a1[1] + a1[2] + a1[3];
  float ts2 = a2[0] + a2[1] + a2[2] + a2[3];
  float mu = ts1 * (1.0f / H_);
  float var = ts2 * (1.0f / H_) - mu * mu;
  float inv = rsqrtf(var + 1e-12f);
  float4 gv = *reinterpret_cast<const float4*>(gam + t * 4);
  float4 bb = *reinterpret_cast<const float4*>(bet + t * 4);
  float4 ov;
  ov.x = (x0 - mu) * inv * gv.x + bb.x;
  ov.y = (x1 - mu) * inv * gv.y + bb.y;
  ov.z = (x2 - mu) * inv * gv.z + bb.z;
  ov.w = (x3 - mu) * inv * gv.w + bb.w;
  *reinterpret_cast<float4*>(out + base) = ov;
}

extern "C" void kernel_launch(void* const* d_in, const int* in_sizes, int n_in,
                              void* d_out, int out_size, void* d_ws, size_t ws_size,
                              hipStream_t stream) {
  const float* hs   = (const float*)d_in[0];
  const float* mask = (const float*)d_in[1];
  const float* Wq   = (const float*)d_in[2];
  const float* bq   = (const float*)d_in[3];
  const float* Wk   = (const float*)d_in[4];
  const float* bk   = (const float*)d_in[5];
  const float* Wv   = (const float*)d_in[6];
  const float* bv   = (const float*)d_in[7];
  const float* Wd   = (const float*)d_in[8];
  const float* bd   = (const float*)d_in[9];
  const float* lng  = (const float*)d_in[10];
  const float* lnb  = (const float*)d_in[11];
  float* out = (float*)d_out;

  char* ws = (char*)d_ws;
  const size_t SZ_X = (size_t)B_ * S_ * H_ * 2;
  const size_t SZ_W = (size_t)H_ * H_ * 2;
  unsigned short* Xb  = (unsigned short*)(ws);
  unsigned short* Wqb = (unsigned short*)(ws + SZ_X);
  unsigned short* Wkb = (unsigned short*)(ws + SZ_X + SZ_W);
  unsigned short* Wvb = (unsigned short*)(ws + SZ_X + 2 * SZ_W);
  unsigned short* Wdb = (unsigned short*)(ws + SZ_X + 3 * SZ_W);
  unsigned short* Qb  = (unsigned short*)(ws + SZ_X + 4 * SZ_W);
  unsigned short* Kb  = (unsigned short*)(ws + 2 * SZ_X + 4 * SZ_W);
  unsigned short* Vb  = (unsigned short*)(ws + 3 * SZ_X + 4 * SZ_W);
  unsigned short* Cxb = (unsigned short*)(ws + 4 * SZ_X + 4 * SZ_W);
  float* Proj         = (float*)(ws + 5 * SZ_X + 4 * SZ_W);

  const int NX = B_ * S_ * H_;
  const int NW = H_ * H_;

  cvt_kernel<<<NX / 1024, 256, 0, stream>>>(hs, Xb, NX);
  cvt_kernel<<<NW / 1024, 256, 0, stream>>>(Wq, Wqb, NW);
  cvt_kernel<<<NW / 1024, 256, 0, stream>>>(Wk, Wkb, NW);
  cvt_kernel<<<NW / 1024, 256, 0, stream>>>(Wv, Wvb, NW);
  cvt_kernel<<<NW / 1024, 256, 0, stream>>>(Wd, Wdb, NW);

  dim3 gg(B_ * S_ / 128, H_ / 128);
  gemm_bt<true><<<gg, 256, 0, stream>>>(Xb, Wqb, bq, Qb, B_ * S_, H_, H_);
  gemm_bt<true><<<gg, 256, 0, stream>>>(Xb, Wkb, bk, Kb, B_ * S_, H_, H_);
  gemm_bt<true><<<gg, 256, 0, stream>>>(Xb, Wvb, bv, Vb, B_ * S_, H_, H_);

  dim3 ga(S_ / 64, NH_, B_);
  attn_kernel<<<ga, 256, 0, stream>>>(Qb, Kb, Vb, mask, Cxb);

  gemm_bt<false><<<gg, 256, 0, stream>>>(Cxb, Wdb, bd, Proj, B_ * S_, H_, H_);

  ln_kernel<<<B_ * S_, 256, 0, stream>>>(Proj, hs, lng, lnb, out);
}

// Round 5
// 330.719 us; speedup vs baseline: 1.5066x; 1.0409x over previous
//
#include <hip/hip_runtime.h>
#include <stdint.h>

#define B_ 4
#define S_ 2048
#define H_ 1024
#define NH_ 16
#define HD_ 64

typedef __bf16 bf16x8 __attribute__((ext_vector_type(8)));
typedef unsigned short u16x8 __attribute__((ext_vector_type(8)));
typedef float f32x4 __attribute__((ext_vector_type(4)));
typedef float f32x16 __attribute__((ext_vector_type(16)));

__device__ __forceinline__ unsigned short f2bf(float x) {
  union { float f; unsigned u; } c; c.f = x;
  unsigned r = (c.u + 0x7FFFu + ((c.u >> 16) & 1u)) >> 16;
  return (unsigned short)r;
}

__device__ __forceinline__ void gload16(const unsigned short* g, unsigned short* lds) {
  __builtin_amdgcn_global_load_lds((const __attribute__((address_space(1))) void*)g,
                                   (__attribute__((address_space(3))) void*)lds, 16, 0, 0);
}

// ---------------- fp32 -> bf16 cast ----------------
__global__ __launch_bounds__(256) void cvt_kernel(const float* __restrict__ src,
                                                  unsigned short* __restrict__ dst, int n) {
  int i = (blockIdx.x * blockDim.x + threadIdx.x) * 4;
  if (i < n) {
    float4 v = *reinterpret_cast<const float4*>(src + i);
    ushort4 o;
    o.x = f2bf(v.x); o.y = f2bf(v.y); o.z = f2bf(v.z); o.w = f2bf(v.w);
    *reinterpret_cast<ushort4*>(dst + i) = o;
  }
}

// ---------------- bf16 GEMM, C[m,n] = sum_k A[m,k]*B[n,k] + bias[n] ----------------
template <bool BF16OUT>
__global__ __launch_bounds__(256) void gemm_bt(const unsigned short* __restrict__ A,
                                               const unsigned short* __restrict__ Bm,
                                               const float* __restrict__ bias,
                                               void* __restrict__ Cout,
                                               int M, int N, int K) {
  __shared__ unsigned short As[128 * 32];
  __shared__ unsigned short Bs[128 * 32];
  const int t = threadIdx.x;
  const int lane = t & 63;
  const int wv = t >> 6;
  const int wm = wv >> 1, wn = wv & 1;
  const int m0 = blockIdx.x * 128, n0 = blockIdx.y * 128;
  const int l15 = lane & 15, g8 = (lane >> 4) * 8;

  f32x4 acc[4][4];
#pragma unroll
  for (int i = 0; i < 4; ++i)
#pragma unroll
    for (int j = 0; j < 4; ++j) { f32x4 z = {0.f, 0.f, 0.f, 0.f}; acc[i][j] = z; }

  const int rowA = t >> 2;
  const int colA = (t & 3) * 8;
  const unsigned short* gA0 = A + (long)(m0 + rowA) * K + colA;
  const unsigned short* gA1 = A + (long)(m0 + 64 + rowA) * K + colA;
  const unsigned short* gB0 = Bm + (long)(n0 + rowA) * K + colA;
  const unsigned short* gB1 = Bm + (long)(n0 + 64 + rowA) * K + colA;
  unsigned short* ldsA0 = &As[wv * 512];
  unsigned short* ldsA1 = &As[2048 + wv * 512];
  unsigned short* ldsB0 = &Bs[wv * 512];
  unsigned short* ldsB1 = &Bs[2048 + wv * 512];

  for (int k0 = 0; k0 < K; k0 += 32) {
    __syncthreads();
    gload16(gA0 + k0, ldsA0);
    gload16(gA1 + k0, ldsA1);
    gload16(gB0 + k0, ldsB0);
    gload16(gB1 + k0, ldsB1);
    __syncthreads();

    bf16x8 af[4], bfr[4];
#pragma unroll
    for (int i = 0; i < 4; ++i)
      af[i] = *reinterpret_cast<const bf16x8*>(&As[(wm * 64 + i * 16 + l15) * 32 + g8]);
#pragma unroll
    for (int j = 0; j < 4; ++j)
      bfr[j] = *reinterpret_cast<const bf16x8*>(&Bs[(wn * 64 + j * 16 + l15) * 32 + g8]);
#pragma unroll
    for (int i = 0; i < 4; ++i)
#pragma unroll
      for (int j = 0; j < 4; ++j)
        acc[i][j] = __builtin_amdgcn_mfma_f32_16x16x32_bf16(af[i], bfr[j], acc[i][j], 0, 0, 0);
  }

  const int r0 = (lane >> 4) * 4;
#pragma unroll
  for (int i = 0; i < 4; ++i)
#pragma unroll
    for (int j = 0; j < 4; ++j) {
      int col = n0 + wn * 64 + j * 16 + l15;
      float bv = bias[col];
#pragma unroll
      for (int r = 0; r < 4; ++r) {
        int row = m0 + wm * 64 + i * 16 + r0 + r;
        float v = acc[i][j][r] + bv;
        if (BF16OUT)
          ((unsigned short*)Cout)[(long)row * N + col] = f2bf(v);
        else
          ((float*)Cout)[(long)row * N + col] = v;
      }
    }
}

// ---------------- flash attention, 32x32x16 MFMA ----------------
// grid (S/128, NH, B), 256 threads = 4 waves; wave owns 32 q-rows. KV staged 64,
// processed as 2 subtiles of 32.
// Layouts (32x32x16): A[m][k]: m=lane&31, k=8*(lane>>5)+j. B[k][n]: n=lane&31,
// k=8*(lane>>5)+j. D: col=lane&31, row=(r&3)+8*(r>>2)+4*(lane>>5).
// QK swapped: S = mfma(K, Q^T): col = q = lane&31 -> softmax lane-local,
// xor-32 reduce. Scores in log2 domain (Q prescaled by 0.125*log2e).
// PV A-frag: per kv-16 chunk, lane needs kv=8h+j of its own q column; half the
// packed words come from the xor-32 partner -> 2x v_permlane32_swap_b32.
// VtT XOR-swizzle as before: elem (d,kv) at d*72 + (kv&7) + 8*((kv>>3)^(d>>3)).
__global__ __launch_bounds__(256) void attn_kernel(const unsigned short* __restrict__ Q,
                                                   const unsigned short* __restrict__ Kg,
                                                   const unsigned short* __restrict__ Vg,
                                                   const float* __restrict__ mask,
                                                   unsigned short* __restrict__ ctx) {
  __shared__ __align__(16) unsigned short Kt[64 * 72];   // [kv][d] padded
  __shared__ __align__(16) unsigned short VtT[64 * 72];  // [d][kv swizzled] padded
  __shared__ __align__(16) float biasL[64];              // mask bias, log2 domain
  __shared__ __align__(16) float alBuf[4][32];           // per-wave row broadcast
  __shared__ int mflag;

  const int t = threadIdx.x, lane = t & 63;
  const int wv = t >> 6;
  const int h = blockIdx.y, b = blockIdx.z;
  const int q0w = blockIdx.x * 128 + wv * 32;
  const int l31 = lane & 31, h2 = lane >> 5;
  const long headoff = (long)h * HD_;
  const float L2E = 1.44269504088896f;
  const float SC = 0.125f * L2E;  // 1/sqrt(64) * log2(e)

  // Q B-fragments: qf[c] holds Q[q=l31][d = 16c + 8*h2 + j], prescaled
  bf16x8 qf[4];
  {
    const unsigned short* Qrow = Q + ((long)(b * S_ + q0w + l31)) * H_ + headoff;
#pragma unroll
    for (int c = 0; c < 4; ++c) {
      bf16x8 raw = *reinterpret_cast<const bf16x8*>(Qrow + 16 * c + 8 * h2);
#pragma unroll
      for (int j = 0; j < 8; ++j) qf[c][j] = (__bf16)((float)raw[j] * SC);
    }
  }

  f32x16 o[2];
#pragma unroll
  for (int dt = 0; dt < 2; ++dt)
#pragma unroll
    for (int r = 0; r < 16; ++r) o[dt][r] = 0.f;
  float mrow = -1.0e30f, lsum = 0.f;  // per lane, q = l31 (log2 domain)

  const unsigned short* KtA = &Kt[l31 * 72 + 8 * h2];  // A-frag base (kv row l31)
  const int rowd0 = l31, rowd1 = 32 + l31;             // V rows for dt=0,1
  const int grp0 = (rowd0 >> 3) & 7, grp1 = (rowd1 >> 3) & 7;

  for (int kv0 = 0; kv0 < S_; kv0 += 64) {
    __syncthreads();
    // ---- stage K (row-major, padded) ----
#pragma unroll
    for (int it = 0; it < 2; ++it) {
      int job = t + it * 256;
      int kv = job >> 3, cg = (job & 7) * 8;
      u16x8 kvv = *reinterpret_cast<const u16x8*>(
          Kg + ((long)(b * S_ + kv0 + kv)) * H_ + headoff + cg);
      *reinterpret_cast<u16x8*>(&Kt[kv * 72 + cg]) = kvv;
    }
    // ---- stage V transposed, XOR swizzle, ushort2 (kv-pair) stores ----
    {
      int p2 = t >> 3, dc = t & 7;
      int kv = p2 * 2;
      const unsigned short* vp0 = Vg + ((long)(b * S_ + kv0 + kv)) * H_ + headoff + dc * 8;
      u16x8 v0 = *reinterpret_cast<const u16x8*>(vp0);
      u16x8 v1 = *reinterpret_cast<const u16x8*>(vp0 + H_);
      int pos = (kv & 7) | (((kv >> 3) ^ dc) << 3);
#pragma unroll
      for (int j = 0; j < 8; ++j) {
        ushort2 pr; pr.x = v0[j]; pr.y = v1[j];
        *reinterpret_cast<ushort2*>(&VtT[(dc * 8 + j) * 72 + pos]) = pr;
      }
    }
    // ---- wave0: mask bias (log2 domain) + nonzero flag ----
    if (t < 64) {
      float mv = mask[b * S_ + kv0 + t];
      bool nz = (mv != 1.0f);
      biasL[t] = (1.f - mv) * (-10000.f * L2E);
      unsigned long long bal = __ballot(nz);
      if (t == 0) mflag = (bal != 0ull);
    }
    __syncthreads();

    // ---- two kv subtiles of 32 ----
#pragma unroll
    for (int kvt = 0; kvt < 2; ++kvt) {
      // QK: S[kv 32][q 32], 4 k-chunks of 16 (d)
      f32x16 sv;
#pragma unroll
      for (int r = 0; r < 16; ++r) sv[r] = 0.f;
#pragma unroll
      for (int c = 0; c < 4; ++c) {
        bf16x8 af = *reinterpret_cast<const bf16x8*>(KtA + (kvt * 32) * 72 + 16 * c);
        sv = __builtin_amdgcn_mfma_f32_32x32x16_bf16(af, qf[c], sv, 0, 0, 0);
      }
      // bias (rare: mask != all-ones)
      if (mflag) {
#pragma unroll
        for (int m = 0; m < 4; ++m) {
          f32x4 bb = *reinterpret_cast<const f32x4*>(&biasL[kvt * 32 + 8 * m + 4 * h2]);
#pragma unroll
          for (int i = 0; i < 4; ++i) sv[4 * m + i] += bb[i];
        }
      }
      // ---- online softmax (log2 domain), defer-max THR=8 ----
      float tm = sv[0];
#pragma unroll
      for (int r = 1; r < 16; ++r) tm = fmaxf(tm, sv[r]);
      tm = fmaxf(tm, __shfl_xor(tm, 32));
      if (!__all(tm <= mrow + 8.0f)) {
        float mn = fmaxf(mrow, tm);
        float al = exp2f(mrow - mn);
        mrow = mn;
        lsum *= al;
        if (lane < 32) alBuf[wv][lane] = al;
        __builtin_amdgcn_wave_barrier();
#pragma unroll
        for (int m = 0; m < 4; ++m) {
          f32x4 av = *reinterpret_cast<const f32x4*>(&alBuf[wv][8 * m + 4 * h2]);
#pragma unroll
          for (int i = 0; i < 4; ++i) {
            o[0][4 * m + i] *= av[i];
            o[1][4 * m + i] *= av[i];
          }
        }
      }
      float ts = 0.f;
#pragma unroll
      for (int r = 0; r < 16; ++r) {
        float p = exp2f(sv[r] - mrow);
        sv[r] = p;
        ts += p;
      }
      ts += __shfl_xor(ts, 32);
      lsum += ts;

      // ---- PV per kv-16 chunk: pack -> permlane swap -> 2 MFMA ----
#pragma unroll
      for (int c2 = 0; c2 < 2; ++c2) {
        int kc = 2 * kvt + c2;
        unsigned p0, p1, p2, p3;
        {
          union { __bf16 e[2]; unsigned w; } u;
          u.e[0] = (__bf16)sv[8 * c2 + 0]; u.e[1] = (__bf16)sv[8 * c2 + 1]; p0 = u.w;
          u.e[0] = (__bf16)sv[8 * c2 + 2]; u.e[1] = (__bf16)sv[8 * c2 + 3]; p1 = u.w;
          u.e[0] = (__bf16)sv[8 * c2 + 4]; u.e[1] = (__bf16)sv[8 * c2 + 5]; p2 = u.w;
          u.e[0] = (__bf16)sv[8 * c2 + 6]; u.e[1] = (__bf16)sv[8 * c2 + 7]; p3 = u.w;
        }
        // swap upper-half(p0) <-> lower-half(p2): after, p0 = frag word0, p2 = word2
        asm("v_permlane32_swap_b32 %0, %1" : "+v"(p0), "+v"(p2));
        asm("v_permlane32_swap_b32 %0, %1" : "+v"(p1), "+v"(p3));
        union { unsigned w[4]; bf16x8 v; } fa;
        fa.w[0] = p0; fa.w[1] = p1; fa.w[2] = p2; fa.w[3] = p3;

        bf16x8 vb0 = *reinterpret_cast<const bf16x8*>(
            &VtT[rowd0 * 72 + 8 * ((2 * kc + h2) ^ grp0)]);
        bf16x8 vb1 = *reinterpret_cast<const bf16x8*>(
            &VtT[rowd1 * 72 + 8 * ((2 * kc + h2) ^ grp1)]);
        o[0] = __builtin_amdgcn_mfma_f32_32x32x16_bf16(fa.v, vb0, o[0], 0, 0, 0);
        o[1] = __builtin_amdgcn_mfma_f32_32x32x16_bf16(fa.v, vb1, o[1], 0, 0, 0);
      }
    }
  }

  // ---- epilogue: 1/lsum broadcast, write ctx ----
  if (lane < 32) alBuf[wv][lane] = 1.0f / lsum;
  __builtin_amdgcn_wave_barrier();
  unsigned short* ctxbase = ctx + ((long)(b * S_ + q0w + 4 * h2)) * H_ + headoff + l31;
#pragma unroll
  for (int m = 0; m < 4; ++m) {
    f32x4 iv = *reinterpret_cast<const f32x4*>(&alBuf[wv][8 * m + 4 * h2]);
#pragma unroll
    for (int i = 0; i < 4; ++i) {
#pragma unroll
      for (int dt = 0; dt < 2; ++dt)
        ctxbase[(long)(8 * m + i) * H_ + dt * 32] = f2bf(o[dt][4 * m + i] * iv[i]);
    }
  }
}

// ---------------- residual + LayerNorm ----------------
__global__ __launch_bounds__(256) void ln_kernel(const float* __restrict__ proj,
                                                 const float* __restrict__ hs,
                                                 const float* __restrict__ gam,
                                                 const float* __restrict__ bet,
                                                 float* __restrict__ out) {
  const int row = blockIdx.x;
  const int t = threadIdx.x;
  const long base = (long)row * H_ + t * 4;
  float4 a = *reinterpret_cast<const float4*>(proj + base);
  float4 hv = *reinterpret_cast<const float4*>(hs + base);
  float x0 = a.x + hv.x, x1 = a.y + hv.y, x2 = a.z + hv.z, x3 = a.w + hv.w;
  float s1 = x0 + x1 + x2 + x3;
  float s2 = x0 * x0 + x1 * x1 + x2 * x2 + x3 * x3;
#pragma unroll
  for (int off = 1; off < 64; off <<= 1) {
    s1 += __shfl_xor(s1, off);
    s2 += __shfl_xor(s2, off);
  }
  __shared__ float a1[4], a2[4];
  if ((t & 63) == 0) { a1[t >> 6] = s1; a2[t >> 6] = s2; }
  __syncthreads();
  float ts1 = a1[0] + a1[1] + a1[2] + a1[3];
  float ts2 = a2[0] + a2[1] + a2[2] + a2[3];
  float mu = ts1 * (1.0f / H_);
  float var = ts2 * (1.0f / H_) - mu * mu;
  float inv = rsqrtf(var + 1e-12f);
  float4 gv = *reinterpret_cast<const float4*>(gam + t * 4);
  float4 bb = *reinterpret_cast<const float4*>(bet + t * 4);
  float4 ov;
  ov.x = (x0 - mu) * inv * gv.x + bb.x;
  ov.y = (x1 - mu) * inv * gv.y + bb.y;
  ov.z = (x2 - mu) * inv * gv.z + bb.z;
  ov.w = (x3 - mu) * inv * gv.w + bb.w;
  *reinterpret_cast<float4*>(out + base) = ov;
}

extern "C" void kernel_launch(void* const* d_in, const int* in_sizes, int n_in,
                              void* d_out, int out_size, void* d_ws, size_t ws_size,
                              hipStream_t stream) {
  const float* hs   = (const float*)d_in[0];
  const float* mask = (const float*)d_in[1];
  const float* Wq   = (const float*)d_in[2];
  const float* bq   = (const float*)d_in[3];
  const float* Wk   = (const float*)d_in[4];
  const float* bk   = (const float*)d_in[5];
  const float* Wv   = (const float*)d_in[6];
  const float* bv   = (const float*)d_in[7];
  const float* Wd   = (const float*)d_in[8];
  const float* bd   = (const float*)d_in[9];
  const float* lng  = (const float*)d_in[10];
  const float* lnb  = (const float*)d_in[11];
  float* out = (float*)d_out;

  char* ws = (char*)d_ws;
  const size_t SZ_X = (size_t)B_ * S_ * H_ * 2;
  const size_t SZ_W = (size_t)H_ * H_ * 2;
  unsigned short* Xb  = (unsigned short*)(ws);
  unsigned short* Wqb = (unsigned short*)(ws + SZ_X);
  unsigned short* Wkb = (unsigned short*)(ws + SZ_X + SZ_W);
  unsigned short* Wvb = (unsigned short*)(ws + SZ_X + 2 * SZ_W);
  unsigned short* Wdb = (unsigned short*)(ws + SZ_X + 3 * SZ_W);
  unsigned short* Qb  = (unsigned short*)(ws + SZ_X + 4 * SZ_W);
  unsigned short* Kb  = (unsigned short*)(ws + 2 * SZ_X + 4 * SZ_W);
  unsigned short* Vb  = (unsigned short*)(ws + 3 * SZ_X + 4 * SZ_W);
  unsigned short* Cxb = (unsigned short*)(ws + 4 * SZ_X + 4 * SZ_W);
  float* Proj         = (float*)(ws + 5 * SZ_X + 4 * SZ_W);

  const int NX = B_ * S_ * H_;
  const int NW = H_ * H_;

  cvt_kernel<<<NX / 1024, 256, 0, stream>>>(hs, Xb, NX);
  cvt_kernel<<<NW / 1024, 256, 0, stream>>>(Wq, Wqb, NW);
  cvt_kernel<<<NW / 1024, 256, 0, stream>>>(Wk, Wkb, NW);
  cvt_kernel<<<NW / 1024, 256, 0, stream>>>(Wv, Wvb, NW);
  cvt_kernel<<<NW / 1024, 256, 0, stream>>>(Wd, Wdb, NW);

  dim3 gg(B_ * S_ / 128, H_ / 128);
  gemm_bt<true><<<gg, 256, 0, stream>>>(Xb, Wqb, bq, Qb, B_ * S_, H_, H_);
  gemm_bt<true><<<gg, 256, 0, stream>>>(Xb, Wkb, bk, Kb, B_ * S_, H_, H_);
  gemm_bt<true><<<gg, 256, 0, stream>>>(Xb, Wvb, bv, Vb, B_ * S_, H_, H_);

  dim3 ga(S_ / 128, NH_, B_);  // (16, 16, 4)
  attn_kernel<<<ga, 256, 0, stream>>>(Qb, Kb, Vb, mask, Cxb);

  gemm_bt<false><<<gg, 256, 0, stream>>>(Cxb, Wdb, bd, Proj, B_ * S_, H_, H_);

  ln_kernel<<<B_ * S_, 256, 0, stream>>>(Proj, hs, lng, lnb, out);
}

// Round 6
// 311.910 us; speedup vs baseline: 1.5974x; 1.0603x over previous
//
#include <hip/hip_runtime.h>
#include <stdint.h>

#define B_ 4
#define S_ 2048
#define H_ 1024
#define NH_ 16
#define HD_ 64

typedef __bf16 bf16x8 __attribute__((ext_vector_type(8)));
typedef unsigned short u16x8 __attribute__((ext_vector_type(8)));
typedef float f32x4 __attribute__((ext_vector_type(4)));
typedef float f32x16 __attribute__((ext_vector_type(16)));

__device__ __forceinline__ unsigned short f2bf(float x) {
  union { float f; unsigned u; } c; c.f = x;
  unsigned r = (c.u + 0x7FFFu + ((c.u >> 16) & 1u)) >> 16;
  return (unsigned short)r;
}

__device__ __forceinline__ void gload16(const unsigned short* g, unsigned short* lds) {
  __builtin_amdgcn_global_load_lds((const __attribute__((address_space(1))) void*)g,
                                   (__attribute__((address_space(3))) void*)lds, 16, 0, 0);
}

// ---------------- fp32 -> bf16 cast ----------------
__global__ __launch_bounds__(256) void cvt_kernel(const float* __restrict__ src,
                                                  unsigned short* __restrict__ dst, int n) {
  int i = (blockIdx.x * blockDim.x + threadIdx.x) * 4;
  if (i < n) {
    float4 v = *reinterpret_cast<const float4*>(src + i);
    ushort4 o;
    o.x = f2bf(v.x); o.y = f2bf(v.y); o.z = f2bf(v.z); o.w = f2bf(v.w);
    *reinterpret_cast<ushort4*>(dst + i) = o;
  }
}

// ---------------- bf16 GEMM, C[m,n] = sum_k A[m,k]*B[n,k] + bias[n] ----------------
template <bool BF16OUT>
__global__ __launch_bounds__(256) void gemm_bt(const unsigned short* __restrict__ A,
                                               const unsigned short* __restrict__ Bm,
                                               const float* __restrict__ bias,
                                               void* __restrict__ Cout,
                                               int M, int N, int K) {
  __shared__ unsigned short As[128 * 32];
  __shared__ unsigned short Bs[128 * 32];
  const int t = threadIdx.x;
  const int lane = t & 63;
  const int wv = t >> 6;
  const int wm = wv >> 1, wn = wv & 1;
  const int m0 = blockIdx.x * 128, n0 = blockIdx.y * 128;
  const int l15 = lane & 15, g8 = (lane >> 4) * 8;

  f32x4 acc[4][4];
#pragma unroll
  for (int i = 0; i < 4; ++i)
#pragma unroll
    for (int j = 0; j < 4; ++j) { f32x4 z = {0.f, 0.f, 0.f, 0.f}; acc[i][j] = z; }

  const int rowA = t >> 2;
  const int colA = (t & 3) * 8;
  const unsigned short* gA0 = A + (long)(m0 + rowA) * K + colA;
  const unsigned short* gA1 = A + (long)(m0 + 64 + rowA) * K + colA;
  const unsigned short* gB0 = Bm + (long)(n0 + rowA) * K + colA;
  const unsigned short* gB1 = Bm + (long)(n0 + 64 + rowA) * K + colA;
  unsigned short* ldsA0 = &As[wv * 512];
  unsigned short* ldsA1 = &As[2048 + wv * 512];
  unsigned short* ldsB0 = &Bs[wv * 512];
  unsigned short* ldsB1 = &Bs[2048 + wv * 512];

  for (int k0 = 0; k0 < K; k0 += 32) {
    __syncthreads();
    gload16(gA0 + k0, ldsA0);
    gload16(gA1 + k0, ldsA1);
    gload16(gB0 + k0, ldsB0);
    gload16(gB1 + k0, ldsB1);
    __syncthreads();

    bf16x8 af[4], bfr[4];
#pragma unroll
    for (int i = 0; i < 4; ++i)
      af[i] = *reinterpret_cast<const bf16x8*>(&As[(wm * 64 + i * 16 + l15) * 32 + g8]);
#pragma unroll
    for (int j = 0; j < 4; ++j)
      bfr[j] = *reinterpret_cast<const bf16x8*>(&Bs[(wn * 64 + j * 16 + l15) * 32 + g8]);
#pragma unroll
    for (int i = 0; i < 4; ++i)
#pragma unroll
      for (int j = 0; j < 4; ++j)
        acc[i][j] = __builtin_amdgcn_mfma_f32_16x16x32_bf16(af[i], bfr[j], acc[i][j], 0, 0, 0);
  }

  const int r0 = (lane >> 4) * 4;
#pragma unroll
  for (int i = 0; i < 4; ++i)
#pragma unroll
    for (int j = 0; j < 4; ++j) {
      int col = n0 + wn * 64 + j * 16 + l15;
      float bv = bias[col];
#pragma unroll
      for (int r = 0; r < 4; ++r) {
        int row = m0 + wm * 64 + i * 16 + r0 + r;
        float v = acc[i][j][r] + bv;
        if (BF16OUT)
          ((unsigned short*)Cout)[(long)row * N + col] = f2bf(v);
        else
          ((float*)Cout)[(long)row * N + col] = v;
      }
    }
}

// ---------------- flash attention, 32x32x16 MFMA, double-buffered staging ----------------
// grid (S/128, NH, B), 256 threads = 4 waves; wave owns 32 q-rows. KV tile 64,
// processed as 2 subtiles of 32. Per iteration: issue next tile's global loads
// to regs -> compute current LDS buffer -> write regs to other buffer -> ONE
// barrier. (Write-to-buf^1 while others still read buf is safe: a wave reaches
// iter t's write only after all waves passed iter t-1's barrier.)
// Layouts (32x32x16): A[m][k]: m=lane&31, k=8*(lane>>5)+j. B[k][n]: n=lane&31.
// D: col=lane&31, row=(r&3)+8*(r>>2)+4*(lane>>5).
// QK swapped: S = mfma(K, Q) -> col = q = lane&31, softmax lane-local, xor-32
// reduce, log2 domain (Q prescaled by 0.125*log2e). PV A-frag via 2x
// v_permlane32_swap_b32 per kv-16 chunk. VtT XOR-swizzle: (d,kv) at
// d*72 + (kv&7) + 8*((kv>>3)^(d>>3)).
__global__ __launch_bounds__(256) void attn_kernel(const unsigned short* __restrict__ Q,
                                                   const unsigned short* __restrict__ Kg,
                                                   const unsigned short* __restrict__ Vg,
                                                   const float* __restrict__ mask,
                                                   unsigned short* __restrict__ ctx) {
  __shared__ __align__(16) unsigned short Kt[2][64 * 72];
  __shared__ __align__(16) unsigned short VtT[2][64 * 72];
  __shared__ __align__(16) float biasL[2][64];
  __shared__ __align__(16) float alBuf[4][32];
  __shared__ int mflag[2];

  const int t = threadIdx.x, lane = t & 63;
  const int wv = t >> 6;
  const int h = blockIdx.y, b = blockIdx.z;
  const int q0w = blockIdx.x * 128 + wv * 32;
  const int l31 = lane & 31, h2 = lane >> 5;
  const long headoff = (long)h * HD_;
  const float L2E = 1.44269504088896f;
  const float SC = 0.125f * L2E;

  // Q B-fragments, prescaled
  bf16x8 qf[4];
  {
    const unsigned short* Qrow = Q + ((long)(b * S_ + q0w + l31)) * H_ + headoff;
#pragma unroll
    for (int c = 0; c < 4; ++c) {
      bf16x8 raw = *reinterpret_cast<const bf16x8*>(Qrow + 16 * c + 8 * h2);
#pragma unroll
      for (int j = 0; j < 8; ++j) qf[c][j] = (__bf16)((float)raw[j] * SC);
    }
  }

  f32x16 o[2];
#pragma unroll
  for (int dt = 0; dt < 2; ++dt)
#pragma unroll
    for (int r = 0; r < 16; ++r) o[dt][r] = 0.f;
  float mrow = -1.0e30f, lsum = 0.f;

  const int rowd0 = l31, rowd1 = 32 + l31;
  const int grp0 = (rowd0 >> 3) & 7, grp1 = (rowd1 >> 3) & 7;

  // staging registers + addresses
  const int krow = t >> 3, kcg = (t & 7) * 8;   // K: rows krow, krow+32
  const int vrow = (t >> 3) * 2, dc = t & 7;    // V: rows vrow, vrow+1, d-block dc
  const long gbase = (long)(b * S_) * H_ + headoff;
  u16x8 kr0, kr1, vr0, vr1;
  float mv = 1.0f;

  auto LOADT = [&](int kv0) {
    kr0 = *reinterpret_cast<const u16x8*>(Kg + gbase + (long)(kv0 + krow) * H_ + kcg);
    kr1 = *reinterpret_cast<const u16x8*>(Kg + gbase + (long)(kv0 + krow + 32) * H_ + kcg);
    vr0 = *reinterpret_cast<const u16x8*>(Vg + gbase + (long)(kv0 + vrow) * H_ + dc * 8);
    vr1 = *reinterpret_cast<const u16x8*>(Vg + gbase + (long)(kv0 + vrow + 1) * H_ + dc * 8);
    if (t < 64) mv = mask[b * S_ + kv0 + t];
  };
  auto WRITET = [&](int buf) {
    *reinterpret_cast<u16x8*>(&Kt[buf][krow * 72 + kcg]) = kr0;
    *reinterpret_cast<u16x8*>(&Kt[buf][(krow + 32) * 72 + kcg]) = kr1;
    const int pos = (vrow & 7) | (((vrow >> 3) ^ dc) << 3);
#pragma unroll
    for (int j = 0; j < 8; ++j) {
      ushort2 pr; pr.x = vr0[j]; pr.y = vr1[j];
      *reinterpret_cast<ushort2*>(&VtT[buf][(dc * 8 + j) * 72 + pos]) = pr;
    }
    if (t < 64) {
      biasL[buf][t] = (1.f - mv) * (-10000.f * L2E);
      unsigned long long bal = __ballot(mv != 1.0f);
      if (t == 0) mflag[buf] = (bal != 0ull);
    }
  };

  const int NT = S_ / 64;
  LOADT(0);
  WRITET(0);
  __syncthreads();

  for (int it = 0; it < NT; ++it) {
    const int cur = it & 1;
    const bool more = (it + 1 < NT);
    if (more) LOADT((it + 1) * 64);   // issue early; latency hides under compute

    const unsigned short* KtA = &Kt[cur][l31 * 72 + 8 * h2];
    const int mf = mflag[cur];

#pragma unroll
    for (int kvt = 0; kvt < 2; ++kvt) {
      f32x16 sv;
#pragma unroll
      for (int r = 0; r < 16; ++r) sv[r] = 0.f;
      __builtin_amdgcn_s_setprio(1);
#pragma unroll
      for (int c = 0; c < 4; ++c) {
        bf16x8 af = *reinterpret_cast<const bf16x8*>(KtA + (kvt * 32) * 72 + 16 * c);
        sv = __builtin_amdgcn_mfma_f32_32x32x16_bf16(af, qf[c], sv, 0, 0, 0);
      }
      __builtin_amdgcn_s_setprio(0);
      if (mf) {
#pragma unroll
        for (int m = 0; m < 4; ++m) {
          f32x4 bb = *reinterpret_cast<const f32x4*>(&biasL[cur][kvt * 32 + 8 * m + 4 * h2]);
#pragma unroll
          for (int i = 0; i < 4; ++i) sv[4 * m + i] += bb[i];
        }
      }
      // ---- online softmax (log2 domain), balanced trees, defer-max THR=8 ----
      float a0 = fmaxf(sv[0], sv[1]), a1 = fmaxf(sv[2], sv[3]);
      float a2 = fmaxf(sv[4], sv[5]), a3 = fmaxf(sv[6], sv[7]);
      float a4 = fmaxf(sv[8], sv[9]), a5 = fmaxf(sv[10], sv[11]);
      float a6 = fmaxf(sv[12], sv[13]), a7 = fmaxf(sv[14], sv[15]);
      float b0 = fmaxf(a0, a1), b1 = fmaxf(a2, a3), b2 = fmaxf(a4, a5), b3 = fmaxf(a6, a7);
      float tm = fmaxf(fmaxf(b0, b1), fmaxf(b2, b3));
      tm = fmaxf(tm, __shfl_xor(tm, 32));
      if (!__all(tm <= mrow + 8.0f)) {
        float mn = fmaxf(mrow, tm);
        float al = exp2f(mrow - mn);
        mrow = mn;
        lsum *= al;
        if (lane < 32) alBuf[wv][lane] = al;
        __builtin_amdgcn_wave_barrier();
#pragma unroll
        for (int m = 0; m < 4; ++m) {
          f32x4 av = *reinterpret_cast<const f32x4*>(&alBuf[wv][8 * m + 4 * h2]);
#pragma unroll
          for (int i = 0; i < 4; ++i) {
            o[0][4 * m + i] *= av[i];
            o[1][4 * m + i] *= av[i];
          }
        }
      }
#pragma unroll
      for (int r = 0; r < 16; ++r) sv[r] = exp2f(sv[r] - mrow);
      {
        float s0 = sv[0] + sv[1], s1 = sv[2] + sv[3], s2 = sv[4] + sv[5], s3 = sv[6] + sv[7];
        float s4 = sv[8] + sv[9], s5 = sv[10] + sv[11], s6 = sv[12] + sv[13], s7 = sv[14] + sv[15];
        float u0 = s0 + s1, u1 = s2 + s3, u2 = s4 + s5, u3 = s6 + s7;
        float ts = (u0 + u1) + (u2 + u3);
        ts += __shfl_xor(ts, 32);
        lsum += ts;
      }

      // ---- PV per kv-16 chunk: pack -> permlane swap -> 2 MFMA ----
#pragma unroll
      for (int c2 = 0; c2 < 2; ++c2) {
        int kc = 2 * kvt + c2;
        unsigned p0, p1, p2, p3;
        {
          union { __bf16 e[2]; unsigned w; } u;
          u.e[0] = (__bf16)sv[8 * c2 + 0]; u.e[1] = (__bf16)sv[8 * c2 + 1]; p0 = u.w;
          u.e[0] = (__bf16)sv[8 * c2 + 2]; u.e[1] = (__bf16)sv[8 * c2 + 3]; p1 = u.w;
          u.e[0] = (__bf16)sv[8 * c2 + 4]; u.e[1] = (__bf16)sv[8 * c2 + 5]; p2 = u.w;
          u.e[0] = (__bf16)sv[8 * c2 + 6]; u.e[1] = (__bf16)sv[8 * c2 + 7]; p3 = u.w;
        }
        asm("v_permlane32_swap_b32 %0, %1" : "+v"(p0), "+v"(p2));
        asm("v_permlane32_swap_b32 %0, %1" : "+v"(p1), "+v"(p3));
        union { unsigned w[4]; bf16x8 v; } fa;
        fa.w[0] = p0; fa.w[1] = p1; fa.w[2] = p2; fa.w[3] = p3;

        bf16x8 vb0 = *reinterpret_cast<const bf16x8*>(
            &VtT[cur][rowd0 * 72 + 8 * ((2 * kc + h2) ^ grp0)]);
        bf16x8 vb1 = *reinterpret_cast<const bf16x8*>(
            &VtT[cur][rowd1 * 72 + 8 * ((2 * kc + h2) ^ grp1)]);
        __builtin_amdgcn_s_setprio(1);
        o[0] = __builtin_amdgcn_mfma_f32_32x32x16_bf16(fa.v, vb0, o[0], 0, 0, 0);
        o[1] = __builtin_amdgcn_mfma_f32_32x32x16_bf16(fa.v, vb1, o[1], 0, 0, 0);
        __builtin_amdgcn_s_setprio(0);
      }
    }

    if (more) {
      WRITET(cur ^ 1);
      __syncthreads();
    }
  }

  // ---- epilogue ----
  if (lane < 32) alBuf[wv][lane] = 1.0f / lsum;
  __builtin_amdgcn_wave_barrier();
  unsigned short* ctxbase = ctx + ((long)(b * S_ + q0w + 4 * h2)) * H_ + headoff + l31;
#pragma unroll
  for (int m = 0; m < 4; ++m) {
    f32x4 iv = *reinterpret_cast<const f32x4*>(&alBuf[wv][8 * m + 4 * h2]);
#pragma unroll
    for (int i = 0; i < 4; ++i) {
#pragma unroll
      for (int dt = 0; dt < 2; ++dt)
        ctxbase[(long)(8 * m + i) * H_ + dt * 32] = f2bf(o[dt][4 * m + i] * iv[i]);
    }
  }
}

// ---------------- residual + LayerNorm ----------------
__global__ __launch_bounds__(256) void ln_kernel(const float* __restrict__ proj,
                                                 const float* __restrict__ hs,
                                                 const float* __restrict__ gam,
                                                 const float* __restrict__ bet,
                                                 float* __restrict__ out) {
  const int row = blockIdx.x;
  const int t = threadIdx.x;
  const long base = (long)row * H_ + t * 4;
  float4 a = *reinterpret_cast<const float4*>(proj + base);
  float4 hv = *reinterpret_cast<const float4*>(hs + base);
  float x0 = a.x + hv.x, x1 = a.y + hv.y, x2 = a.z + hv.z, x3 = a.w + hv.w;
  float s1 = x0 + x1 + x2 + x3;
  float s2 = x0 * x0 + x1 * x1 + x2 * x2 + x3 * x3;
#pragma unroll
  for (int off = 1; off < 64; off <<= 1) {
    s1 += __shfl_xor(s1, off);
    s2 += __shfl_xor(s2, off);
  }
  __shared__ float a1[4], a2[4];
  if ((t & 63) == 0) { a1[t >> 6] = s1; a2[t >> 6] = s2; }
  __syncthreads();
  float ts1 = a1[0] + a1[1] + a1[2] + a1[3];
  float ts2 = a2[0] + a2[1] + a2[2] + a2[3];
  float mu = ts1 * (1.0f / H_);
  float var = ts2 * (1.0f / H_) - mu * mu;
  float inv = rsqrtf(var + 1e-12f);
  float4 gv = *reinterpret_cast<const float4*>(gam + t * 4);
  float4 bb = *reinterpret_cast<const float4*>(bet + t * 4);
  float4 ov;
  ov.x = (x0 - mu) * inv * gv.x + bb.x;
  ov.y = (x1 - mu) * inv * gv.y + bb.y;
  ov.z = (x2 - mu) * inv * gv.z + bb.z;
  ov.w = (x3 - mu) * inv * gv.w + bb.w;
  *reinterpret_cast<float4*>(out + base) = ov;
}

extern "C" void kernel_launch(void* const* d_in, const int* in_sizes, int n_in,
                              void* d_out, int out_size, void* d_ws, size_t ws_size,
                              hipStream_t stream) {
  const float* hs   = (const float*)d_in[0];
  const float* mask = (const float*)d_in[1];
  const float* Wq   = (const float*)d_in[2];
  const float* bq   = (const float*)d_in[3];
  const float* Wk   = (const float*)d_in[4];
  const float* bk   = (const float*)d_in[5];
  const float* Wv   = (const float*)d_in[6];
  const float* bv   = (const float*)d_in[7];
  const float* Wd   = (const float*)d_in[8];
  const float* bd   = (const float*)d_in[9];
  const float* lng  = (const float*)d_in[10];
  const float* lnb  = (const float*)d_in[11];
  float* out = (float*)d_out;

  char* ws = (char*)d_ws;
  const size_t SZ_X = (size_t)B_ * S_ * H_ * 2;
  const size_t SZ_W = (size_t)H_ * H_ * 2;
  unsigned short* Xb  = (unsigned short*)(ws);
  unsigned short* Wqb = (unsigned short*)(ws + SZ_X);
  unsigned short* Wkb = (unsigned short*)(ws + SZ_X + SZ_W);
  unsigned short* Wvb = (unsigned short*)(ws + SZ_X + 2 * SZ_W);
  unsigned short* Wdb = (unsigned short*)(ws + SZ_X + 3 * SZ_W);
  unsigned short* Qb  = (unsigned short*)(ws + SZ_X + 4 * SZ_W);
  unsigned short* Kb  = (unsigned short*)(ws + 2 * SZ_X + 4 * SZ_W);
  unsigned short* Vb  = (unsigned short*)(ws + 3 * SZ_X + 4 * SZ_W);
  unsigned short* Cxb = (unsigned short*)(ws + 4 * SZ_X + 4 * SZ_W);
  float* Proj         = (float*)(ws + 5 * SZ_X + 4 * SZ_W);

  const int NX = B_ * S_ * H_;
  const int NW = H_ * H_;

  cvt_kernel<<<NX / 1024, 256, 0, stream>>>(hs, Xb, NX);
  cvt_kernel<<<NW / 1024, 256, 0, stream>>>(Wq, Wqb, NW);
  cvt_kernel<<<NW / 1024, 256, 0, stream>>>(Wk, Wkb, NW);
  cvt_kernel<<<NW / 1024, 256, 0, stream>>>(Wv, Wvb, NW);
  cvt_kernel<<<NW / 1024, 256, 0, stream>>>(Wd, Wdb, NW);

  dim3 gg(B_ * S_ / 128, H_ / 128);
  gemm_bt<true><<<gg, 256, 0, stream>>>(Xb, Wqb, bq, Qb, B_ * S_, H_, H_);
  gemm_bt<true><<<gg, 256, 0, stream>>>(Xb, Wkb, bk, Kb, B_ * S_, H_, H_);
  gemm_bt<true><<<gg, 256, 0, stream>>>(Xb, Wvb, bv, Vb, B_ * S_, H_, H_);

  dim3 ga(S_ / 128, NH_, B_);  // (16, 16, 4)
  attn_kernel<<<ga, 256, 0, stream>>>(Qb, Kb, Vb, mask, Cxb);

  gemm_bt<false><<<gg, 256, 0, stream>>>(Cxb, Wdb, bd, Proj, B_ * S_, H_, H_);

  ln_kernel<<<B_ * S_, 256, 0, stream>>>(Proj, hs, lng, lnb, out);
}